// Round 13
// baseline (301.671 us; speedup 1.0000x reference)
//
#include <hip/hip_runtime.h>
#include <hip/hip_cooperative_groups.h>
#include <math.h>

namespace cg = cooperative_groups;

#define B_    2
#define SEQ_  2048
#define D_    256
#define H_    8
#define DK_   32
#define L_    2
#define DFF_  1024

#define TD_CUT 44.0f

typedef short  bf16x8 __attribute__((ext_vector_type(8)));
typedef float  f32x4  __attribute__((ext_vector_type(4)));

__device__ __forceinline__ int compute_kcut(float tdv) {
    int kcut = SEQ_;
    if (tdv > 1e-9f) {
        float kc = TD_CUT / tdv;
        kcut = (kc >= (float)SEQ_) ? SEQ_ : ((int)kc + 1);
    }
    int kcr = (kcut + 31) & ~31;
    if (kcr > SEQ_) kcr = SEQ_;
    return kcr;
}

__device__ __forceinline__ unsigned short f2bf(float f) {
    unsigned int u = __float_as_uint(f);
    unsigned int r = u + 0x7FFFu + ((u >> 16) & 1u);   // RNE
    return (unsigned short)(r >> 16);
}
__device__ __forceinline__ float bf2f(unsigned short u) {
    return __uint_as_float(((unsigned int)u) << 16);
}

__device__ __forceinline__ void gload_lds16(const unsigned short* g, unsigned short* l) {
    __builtin_amdgcn_global_load_lds(
        (const __attribute__((address_space(1))) unsigned int*)(const unsigned int*)g,
        (__attribute__((address_space(3))) unsigned int*)(unsigned int*)l,
        16, 0, 0);
}

// ---------------------------------------------------------------------------
struct MP {
    const float *x, *conv_w, *conv_b, *bn_g, *bn_b, *pe;
    const float *qW, *kW, *vW, *oW, *f1W, *f2W;
    const float *qb, *kb, *vb, *ob, *scale, *td;
    const float *ln1g, *ln1b, *f1b, *f2b, *ln2g, *ln2b, *outW, *outb;
    float *h, *h1, *part, *vtail, *out;
    unsigned short *h_bf, *ctx_bf, *q_bf, *k_bf, *v_bf, *h1_bf;
    unsigned short *wq, *wk, *wv, *wo, *wf1, *wf2;
};

union Smem {
    struct {                                     // qkv
        unsigned short As[64 * 64];
        unsigned short Bs[64 * 64];
        float vsc[4][2][16];
    } qk;
    struct {                                     // attention
        float kt[32][36];
        float vt[32][36];
        float Os[4][64][36];
        float ms[4][64];
        float ls[4][64];
        float vts[32];
    } at;
    struct {                                     // o-proj + LN1
        unsigned short As[16 * 64];
        unsigned short Bs[256 * 64];
        float lsum[4][16], lsq[4][16], mean_s[16], inv_s[16];
    } op;
    struct {                                     // fused FFN
        unsigned short As[32 * 64];
        unsigned short Bs[256 * 64];
        unsigned short ffs[32 * 264];
    } ff;
};

// ---------------------------------------------------------------------------
// Stage: prep (weight cvt + conv/pe + vtail zero). Grid-stride over nb blocks.
// ---------------------------------------------------------------------------
__device__ void prep_stage(const MP& P, int bx, int nb, int tid)
{
    if (bx < 2 * L_) P.vtail[bx * 256 + tid] = 0.f;      // L*B*256 floats

    for (int t = bx * 256 + tid; t < 196608; t += nb * 256) {
        const float* src; unsigned short* dst; int base;
        if (t < 65536) {
            int a = t >> 14;
            src = a == 0 ? P.qW : a == 1 ? P.kW : a == 2 ? P.vW : P.oW;
            dst = a == 0 ? P.wq : a == 1 ? P.wk : a == 2 ? P.wv : P.wo;
            base = (t & 16383) * 8;
        } else {
            int u = t - 65536;
            int a = u >> 16;
            src = a ? P.f2W : P.f1W;
            dst = a ? P.wf2 : P.wf1;
            base = (u & 65535) * 8;
        }
        float4 v0 = *(const float4*)(src + base);
        float4 v1 = *(const float4*)(src + base + 4);
        bf16x8 o;
        o[0] = (short)f2bf(v0.x); o[1] = (short)f2bf(v0.y);
        o[2] = (short)f2bf(v0.z); o[3] = (short)f2bf(v0.w);
        o[4] = (short)f2bf(v1.x); o[5] = (short)f2bf(v1.y);
        o[6] = (short)f2bf(v1.z); o[7] = (short)f2bf(v1.w);
        *(bf16x8*)(dst + base) = o;
    }

    for (int idx = bx * 256 + tid; idx < (int)(B_ * SEQ_ * D_); idx += nb * 256) {
        int d = idx & 255;
        int s = (idx >> 8) & 2047;
        int b = idx >> 19;
        const float* xp = P.x + b * SEQ_;
        float xm1 = (s > 0)        ? xp[s - 1] : 0.f;
        float x0  = xp[s];
        float xp1 = (s < SEQ_ - 1) ? xp[s + 1] : 0.f;
        float acc = xm1 * P.conv_w[d * 3 + 0] + x0 * P.conv_w[d * 3 + 1] + xp1 * P.conv_w[d * 3 + 2];
        acc += P.conv_b[d];
        acc = acc * rsqrtf(1.f + 1e-5f) * P.bn_g[d] + P.bn_b[d];
        acc = fmaxf(acc, 0.f);
        float v = acc + P.pe[s * D_ + d];
        P.h[idx] = v;
        P.h_bf[idx] = f2bf(v);
    }
}

// ---------------------------------------------------------------------------
// Stage: q/k/v GEMM (BK=64) + fused vtail atomic accumulation (z==2)
// ---------------------------------------------------------------------------
__device__ void qkv_stage(Smem& S, int w,
    const unsigned short* A,
    const unsigned short* W0, const unsigned short* W1, const unsigned short* W2,
    const float* b0, const float* b1, const float* b2,
    unsigned short* O0, unsigned short* O1, unsigned short* O2,
    const float* td_l, float* vtail_l, int tid)
{
    int x = w & 3, y = (w >> 2) & 63, z = w >> 8;
    const unsigned short* W = (z == 0) ? W0 : (z == 1) ? W1 : W2;
    const float* bias = (z == 0) ? b0 : (z == 1) ? b1 : b2;
    unsigned short* C = (z == 0) ? O0 : (z == 1) ? O1 : O2;
    const int K = 256, N = 256;

    int wave = tid >> 6, lane = tid & 63;
    int wm = (wave & 1) * 32, wn = (wave >> 1) * 32;
    int bm = y * 64, bn = x * 64;

    const unsigned short* aG[2]; unsigned short* aL[2];
    const unsigned short* wG[2]; unsigned short* bL[2];
#pragma unroll
    for (int i = 0; i < 2; ++i) {
        int s = i * 256 + tid;
        int r = s >> 3, cb8 = s & 7;
        int gofs = ((cb8 ^ (r & 7)) * 8);
        aG[i] = A + (size_t)(bm + r) * K + gofs;
        aL[i] = &S.qk.As[s * 8];
        wG[i] = W + (size_t)(bn + r) * K + gofs;
        bL[i] = &S.qk.Bs[s * 8];
    }

    int fr = lane & 15, kb = lane >> 4;
    int swz = fr & 7;

    f32x4 acc[2][2];
#pragma unroll
    for (int i = 0; i < 2; ++i)
#pragma unroll
        for (int j = 0; j < 2; ++j) acc[i][j] = (f32x4){0.f, 0.f, 0.f, 0.f};

    for (int k0 = 0; k0 < K; k0 += 64) {
        __syncthreads();
#pragma unroll
        for (int i = 0; i < 2; ++i) {
            gload_lds16(aG[i] + k0, aL[i]);
            gload_lds16(wG[i] + k0, bL[i]);
        }
        __syncthreads();
#pragma unroll
        for (int kc = 0; kc < 2; ++kc) {
            int blk = ((kc * 4 + kb) ^ swz) * 8;
            bf16x8 a0f = *(const bf16x8*)&S.qk.As[(wm + fr) * 64 + blk];
            bf16x8 a1f = *(const bf16x8*)&S.qk.As[(wm + 16 + fr) * 64 + blk];
            bf16x8 b0f = *(const bf16x8*)&S.qk.Bs[(wn + fr) * 64 + blk];
            bf16x8 b1f = *(const bf16x8*)&S.qk.Bs[(wn + 16 + fr) * 64 + blk];
            acc[0][0] = __builtin_amdgcn_mfma_f32_16x16x32_bf16(a0f, b0f, acc[0][0], 0, 0, 0);
            acc[0][1] = __builtin_amdgcn_mfma_f32_16x16x32_bf16(a0f, b1f, acc[0][1], 0, 0, 0);
            acc[1][0] = __builtin_amdgcn_mfma_f32_16x16x32_bf16(a1f, b0f, acc[1][0], 0, 0, 0);
            acc[1][1] = __builtin_amdgcn_mfma_f32_16x16x32_bf16(a1f, b1f, acc[1][1], 0, 0, 0);
        }
    }

    int crow = (lane >> 4) * 4;
    int ccol = lane & 15;
    float psum[2] = {0.f, 0.f};
    int kc2[2];
    kc2[0] = compute_kcut(td_l[(bn + wn) >> 5]);
    kc2[1] = compute_kcut(td_l[(bn + wn + 16) >> 5]);

#pragma unroll
    for (int j = 0; j < 2; ++j) {
        float bj = bias[bn + wn + j * 16 + ccol];
#pragma unroll
        for (int i = 0; i < 2; ++i) {
#pragma unroll
            for (int r = 0; r < 4; ++r) {
                float v = acc[i][j][r] + bj;
                unsigned short ubf = f2bf(v);
                C[(size_t)(bm + wm + i * 16 + crow + r) * N + bn + wn + j * 16 + ccol] = ubf;
                if (z == 2) {
                    int srow = (bm + wm + i * 16 + crow + r) & 2047;
                    if (srow >= kc2[j]) psum[j] += bf2f(ubf);
                }
            }
        }
    }

    if (z == 2) {
#pragma unroll
        for (int j = 0; j < 2; ++j) {
            psum[j] += __shfl_xor(psum[j], 16);
            psum[j] += __shfl_xor(psum[j], 32);
        }
        if (lane < 16) { S.qk.vsc[wave][0][lane] = psum[0]; S.qk.vsc[wave][1][lane] = psum[1]; }
        __syncthreads();
        if (tid < 64) {
            int wh = tid >> 5, jj = (tid >> 4) & 1, cc = tid & 15;
            float s = S.qk.vsc[2 * wh][jj][cc] + S.qk.vsc[2 * wh + 1][jj][cc];
            int b = y >> 5;
            atomicAdd(&vtail_l[b * 256 + bn + wh * 32 + jj * 16 + cc], s);
        }
        __syncthreads();
    }
}

// ---------------------------------------------------------------------------
// Stage: attention. One 256-thread item = 64 q-rows of one (b,h).
// p in [0,512): b = p>>8, hh = (p>>5)&7, x = p&31 -> rows [x*64, x*64+64).
// ---------------------------------------------------------------------------
__device__ void attn_stage(Smem& S, int p,
    const unsigned short* q, const unsigned short* k, const unsigned short* v,
    const float* vtail_l, unsigned short* ctxbf,
    const float* scale_p, const float* td_l, int tid)
{
    auto& A = S.at;
    int b = p >> 8, hh = (p >> 5) & 7, x = p & 31;
    int t127 = tid & 127;
    int row = (tid >> 7) * 32 + (t127 >> 2);     // 0..63
    int sp = t127 & 3;
    int qrow = x * 64 + row;

    float sc  = 0.17677669529663687f * scale_p[0];
    float tdv = td_l[hh];
    int kcr = compute_kcut(tdv);
    int ntiles = kcr >> 5;

    if (tid < 32) A.vts[tid] = vtail_l[b * 256 + hh * 32 + tid];

    const unsigned short* qptr = q + ((size_t)(b * SEQ_ + qrow)) * D_ + hh * DK_;
    float qreg[32];
#pragma unroll
    for (int j = 0; j < 4; ++j) {
        uint4 u = ((const uint4*)qptr)[j];
        qreg[j*8+0] = __uint_as_float(u.x << 16); qreg[j*8+1] = __uint_as_float(u.x & 0xFFFF0000u);
        qreg[j*8+2] = __uint_as_float(u.y << 16); qreg[j*8+3] = __uint_as_float(u.y & 0xFFFF0000u);
        qreg[j*8+4] = __uint_as_float(u.z << 16); qreg[j*8+5] = __uint_as_float(u.z & 0xFFFF0000u);
        qreg[j*8+6] = __uint_as_float(u.w << 16); qreg[j*8+7] = __uint_as_float(u.w & 0xFFFF0000u);
    }
    float O[32];
#pragma unroll
    for (int d = 0; d < 32; ++d) O[d] = 0.f;
    float mrun = -1e30f, lrun = 0.f;

    for (int t = 0; t < ntiles; ++t) {
        int k0 = t * 32;
        __syncthreads();
        {
            int r = tid >> 3, c4 = (tid & 7) * 4;
            size_t goff = ((size_t)(b * SEQ_ + k0 + r)) * D_ + hh * DK_ + c4;
            uint2 uk = *(const uint2*)(k + goff);
            uint2 uv = *(const uint2*)(v + goff);
            A.kt[r][c4+0] = __uint_as_float(uk.x << 16);
            A.kt[r][c4+1] = __uint_as_float(uk.x & 0xFFFF0000u);
            A.kt[r][c4+2] = __uint_as_float(uk.y << 16);
            A.kt[r][c4+3] = __uint_as_float(uk.y & 0xFFFF0000u);
            A.vt[r][c4+0] = __uint_as_float(uv.x << 16);
            A.vt[r][c4+1] = __uint_as_float(uv.x & 0xFFFF0000u);
            A.vt[r][c4+2] = __uint_as_float(uv.y << 16);
            A.vt[r][c4+3] = __uint_as_float(uv.y & 0xFFFF0000u);
        }
        __syncthreads();

        float sb[8];
        float tmax = -1e30f;
#pragma unroll
        for (int kk = 0; kk < 8; ++kk) {
            int kl = sp * 8 + kk;
            float acc = 0.f;
#pragma unroll
            for (int d4 = 0; d4 < 8; ++d4) {
                float4 kv = *(const float4*)&A.kt[kl][d4 * 4];
                acc += qreg[d4 * 4 + 0] * kv.x + qreg[d4 * 4 + 1] * kv.y
                     + qreg[d4 * 4 + 2] * kv.z + qreg[d4 * 4 + 3] * kv.w;
            }
            float dec = __expf(-tdv * (float)(k0 + kl));
            float sv = acc * sc * dec;
            sb[kk] = sv;
            tmax = fmaxf(tmax, sv);
        }
        float mnew = fmaxf(mrun, tmax);
        float alpha = __expf(mrun - mnew);
        lrun *= alpha;
#pragma unroll
        for (int d = 0; d < 32; ++d) O[d] *= alpha;
#pragma unroll
        for (int kk = 0; kk < 8; ++kk) {
            int kl = sp * 8 + kk;
            float sv = sb[kk];
            float e = __expf(sv - mnew);
            float sg = 1.f / (1.f + __expf(-sv));
            float pw = e * sg;
            lrun += e;
#pragma unroll
            for (int d4 = 0; d4 < 8; ++d4) {
                float4 vv = *(const float4*)&A.vt[kl][d4 * 4];
                O[d4 * 4 + 0] += pw * vv.x; O[d4 * 4 + 1] += pw * vv.y;
                O[d4 * 4 + 2] += pw * vv.z; O[d4 * 4 + 3] += pw * vv.w;
            }
        }
        mrun = mnew;
    }

#pragma unroll
    for (int d4 = 0; d4 < 8; ++d4)
        *(float4*)&A.Os[sp][row][d4 * 4] =
            make_float4(O[d4*4+0], O[d4*4+1], O[d4*4+2], O[d4*4+3]);
    A.ms[sp][row] = mrun;
    A.ls[sp][row] = lrun;
    __syncthreads();

    {
        int mrow = tid >> 2, gg = tid & 3;
        float m0 = fmaxf(fmaxf(A.ms[0][mrow], A.ms[1][mrow]), fmaxf(A.ms[2][mrow], A.ms[3][mrow]));
        float mt = (kcr < SEQ_) ? fmaxf(m0, 0.f) : m0;
        float w0 = __expf(A.ms[0][mrow] - mt), w1 = __expf(A.ms[1][mrow] - mt);
        float w2 = __expf(A.ms[2][mrow] - mt), w3 = __expf(A.ms[3][mrow] - mt);
        float Lt = A.ls[0][mrow]*w0 + A.ls[1][mrow]*w1 + A.ls[2][mrow]*w2 + A.ls[3][mrow]*w3;
        float ew = 0.f;
        if (kcr < SEQ_) {
            ew = __expf(-mt);
            Lt += (float)(SEQ_ - kcr) * ew;
        }
        float invL = 1.f / Lt;
        unsigned int packed[4];
#pragma unroll
        for (int dd = 0; dd < 8; dd += 2) {
            int d0 = gg * 8 + dd, d1 = d0 + 1;
            float n0 = A.Os[0][mrow][d0]*w0 + A.Os[1][mrow][d0]*w1 + A.Os[2][mrow][d0]*w2 + A.Os[3][mrow][d0]*w3;
            float n1 = A.Os[0][mrow][d1]*w0 + A.Os[1][mrow][d1]*w1 + A.Os[2][mrow][d1]*w2 + A.Os[3][mrow][d1]*w3;
            if (kcr < SEQ_) {
                n0 += 0.5f * ew * A.vts[d0];
                n1 += 0.5f * ew * A.vts[d1];
            }
            packed[dd >> 1] = (unsigned)f2bf(n0 * invL) | ((unsigned)f2bf(n1 * invL) << 16);
        }
        unsigned short* obf = ctxbf + ((size_t)(b * SEQ_ + x * 64 + mrow)) * D_ + hh * DK_ + gg * 8;
        *(uint4*)obf = make_uint4(packed[0], packed[1], packed[2], packed[3]);
    }
    __syncthreads();
}

// ---------------------------------------------------------------------------
// Stage: o-proj + residual + LN1. w in [0,512): bm = w*8.
// ---------------------------------------------------------------------------
__device__ void oproj_stage(Smem& S, int w,
    const unsigned short* ctx, const unsigned short* wo,
    const float* ob, const float* resid,
    const float* g1, const float* bt1,
    float* h1out, unsigned short* h1bf, int tid)
{
    auto& O = S.op;
    int wave = tid >> 6, lane = tid & 63;
    int bm = w * 8;
    int fr = lane & 15, kb = lane >> 4;
    int q = kb, cl = fr;
    int swz = fr & 7;

    ((unsigned int*)O.As)[256 + tid] = 0u;       // zero rows 8..15

    const unsigned short* gA = nullptr;
    unsigned short* lA = nullptr;
    if (tid < 64) {
        int r = tid >> 3, cb8 = tid & 7;
        gA = ctx + (size_t)(bm + r) * 256 + ((cb8 ^ (r & 7)) * 8);
        lA = &O.As[tid * 8];
    }

    f32x4 acc[4];
#pragma unroll
    for (int j = 0; j < 4; ++j) acc[j] = (f32x4){0.f, 0.f, 0.f, 0.f};

    for (int k0 = 0; k0 < 256; k0 += 64) {
        __syncthreads();
        if (tid < 64) gload_lds16(gA + k0, lA);
#pragma unroll
        for (int i = 0; i < 8; ++i) {
            int s = i * 256 + tid;
            int r = s >> 3, cb8 = s & 7;
            gload_lds16(wo + (size_t)r * 256 + k0 + ((cb8 ^ (r & 7)) * 8), &O.Bs[s * 8]);
        }
        __syncthreads();
#pragma unroll
        for (int kc = 0; kc < 2; ++kc) {
            int blk = ((kc * 4 + kb) ^ swz) * 8;
            bf16x8 af = *(const bf16x8*)&O.As[fr * 64 + blk];
#pragma unroll
            for (int t = 0; t < 4; ++t) {
                int n = wave * 64 + t * 16 + fr;
                bf16x8 bfv = *(const bf16x8*)&O.Bs[n * 64 + blk];
                acc[t] = __builtin_amdgcn_mfma_f32_16x16x32_bf16(af, bfv, acc[t], 0, 0, 0);
            }
        }
    }

    float zsum[4] = {0.f, 0.f, 0.f, 0.f}, zsq[4] = {0.f, 0.f, 0.f, 0.f};
    float zv[4][4];
#pragma unroll
    for (int ct = 0; ct < 4; ++ct) {
        int col = wave * 64 + ct * 16 + cl;
        float bj = ob[col];
#pragma unroll
        for (int r = 0; r < 4; ++r) {
            int lr = q * 4 + r;
            float z = 0.f;
            if (lr < 8) z = acc[ct][r] + bj + resid[(size_t)(bm + lr) * 256 + col];
            zv[ct][r] = z;
            zsum[r] += z;
            zsq[r]  += z * z;
        }
    }
#pragma unroll
    for (int r = 0; r < 4; ++r) {
#pragma unroll
        for (int off = 1; off < 16; off <<= 1) {
            zsum[r] += __shfl_xor(zsum[r], off);
            zsq[r]  += __shfl_xor(zsq[r], off);
        }
    }
    if (cl == 0) {
#pragma unroll
        for (int r = 0; r < 4; ++r) {
            O.lsum[wave][q * 4 + r] = zsum[r];
            O.lsq[wave][q * 4 + r]  = zsq[r];
        }
    }
    __syncthreads();
    if (tid < 16) {
        float s  = O.lsum[0][tid] + O.lsum[1][tid] + O.lsum[2][tid] + O.lsum[3][tid];
        float sq = O.lsq[0][tid] + O.lsq[1][tid] + O.lsq[2][tid] + O.lsq[3][tid];
        float mean = s * (1.f / 256.f);
        float var  = sq * (1.f / 256.f) - mean * mean;
        O.mean_s[tid] = mean;
        O.inv_s[tid]  = rsqrtf(var + 1e-5f);
    }
    __syncthreads();

#pragma unroll
    for (int ct = 0; ct < 4; ++ct) {
        int col = wave * 64 + ct * 16 + cl;
        float gc = g1[col], bc = bt1[col];
#pragma unroll
        for (int r = 0; r < 4; ++r) {
            int lr = q * 4 + r;
            if (lr < 8) {
                float o = (zv[ct][r] - O.mean_s[lr]) * O.inv_s[lr] * gc + bc;
                size_t off = (size_t)(bm + lr) * 256 + col;
                h1out[off] = o;
                h1bf[off]  = f2bf(o);
            }
        }
    }
    __syncthreads();
}

// ---------------------------------------------------------------------------
// Stage: fused FFN chunk. w in [0,512): c = w>>7, bm = (w&127)*32.
// ---------------------------------------------------------------------------
__device__ void ffn_stage(Smem& S, int w,
    const unsigned short* h1bf, const unsigned short* w1,
    const float* f1b, const unsigned short* w2,
    float* part, int tid)
{
    auto& F = S.ff;
    int wave = tid >> 6, lane = tid & 63;
    int c = w >> 7;
    int bm = (w & 127) * 32;
    int fr = lane & 15, kb = lane >> 4;
    int q = kb, cl = fr;
    int swz = fr & 7;

    int ar = tid >> 3, acb = tid & 7;
    const unsigned short* gA = h1bf + (size_t)(bm + ar) * 256 + ((acb ^ (ar & 7)) * 8);
    unsigned short* lA = &F.As[tid * 8];

    f32x4 a1[2][4];
#pragma unroll
    for (int i = 0; i < 2; ++i)
#pragma unroll
        for (int j = 0; j < 4; ++j) a1[i][j] = (f32x4){0.f, 0.f, 0.f, 0.f};

    for (int k0 = 0; k0 < 256; k0 += 64) {
        __syncthreads();
        gload_lds16(gA + k0, lA);
#pragma unroll
        for (int i = 0; i < 8; ++i) {
            int s = i * 256 + tid;
            int r = s >> 3, cb8 = s & 7;
            gload_lds16(w1 + (size_t)(c * 256 + r) * 256 + k0 + ((cb8 ^ (r & 7)) * 8), &F.Bs[s * 8]);
        }
        __syncthreads();
#pragma unroll
        for (int kc = 0; kc < 2; ++kc) {
            int blk = ((kc * 4 + kb) ^ swz) * 8;
            bf16x8 af[2], bfv[4];
#pragma unroll
            for (int t = 0; t < 2; ++t) af[t] = *(const bf16x8*)&F.As[(t * 16 + fr) * 64 + blk];
#pragma unroll
            for (int t = 0; t < 4; ++t) {
                int n = wave * 64 + t * 16 + fr;
                bfv[t] = *(const bf16x8*)&F.Bs[n * 64 + blk];
            }
#pragma unroll
            for (int i = 0; i < 2; ++i)
#pragma unroll
                for (int j = 0; j < 4; ++j)
                    a1[i][j] = __builtin_amdgcn_mfma_f32_16x16x32_bf16(af[i], bfv[j], a1[i][j], 0, 0, 0);
        }
    }

#pragma unroll
    for (int ct = 0; ct < 4; ++ct) {
        int col = wave * 64 + ct * 16 + cl;
        float bj = f1b[c * 256 + col];
#pragma unroll
        for (int rt = 0; rt < 2; ++rt)
#pragma unroll
            for (int r = 0; r < 4; ++r) {
                float v = fmaxf(a1[rt][ct][r] + bj, 0.f);
                F.ffs[(rt * 16 + q * 4 + r) * 264 + col] = f2bf(v);
            }
    }

    f32x4 a2[2][4];
#pragma unroll
    for (int i = 0; i < 2; ++i)
#pragma unroll
        for (int j = 0; j < 4; ++j) a2[i][j] = (f32x4){0.f, 0.f, 0.f, 0.f};

    for (int k0 = 0; k0 < 256; k0 += 64) {
        __syncthreads();
#pragma unroll
        for (int i = 0; i < 8; ++i) {
            int s = i * 256 + tid;
            int r = s >> 3, cb8 = s & 7;
            gload_lds16(w2 + (size_t)r * 1024 + c * 256 + k0 + ((cb8 ^ (r & 7)) * 8), &F.Bs[s * 8]);
        }
        __syncthreads();
#pragma unroll
        for (int kc = 0; kc < 2; ++kc) {
            int blk = ((kc * 4 + kb) ^ swz) * 8;
            bf16x8 af[2], bfv[4];
#pragma unroll
            for (int t = 0; t < 2; ++t)
                af[t] = *(const bf16x8*)&F.ffs[(t * 16 + fr) * 264 + k0 + kc * 32 + kb * 8];
#pragma unroll
            for (int t = 0; t < 4; ++t) {
                int n = wave * 64 + t * 16 + fr;
                bfv[t] = *(const bf16x8*)&F.Bs[n * 64 + blk];
            }
#pragma unroll
            for (int i = 0; i < 2; ++i)
#pragma unroll
                for (int j = 0; j < 4; ++j)
                    a2[i][j] = __builtin_amdgcn_mfma_f32_16x16x32_bf16(af[i], bfv[j], a2[i][j], 0, 0, 0);
        }
    }

#pragma unroll
    for (int ct = 0; ct < 4; ++ct) {
        int col = wave * 64 + ct * 16 + cl;
#pragma unroll
        for (int rt = 0; rt < 2; ++rt)
#pragma unroll
            for (int r = 0; r < 4; ++r)
                part[((size_t)c * 4096 + bm + rt * 16 + q * 4 + r) * 256 + col] = a2[rt][ct][r];
    }
    __syncthreads();
}

// ---------------------------------------------------------------------------
// Stage: merge FFN2 partials + bias + h1 residual + LN2 (+final fold).
// w in [0,1024): rows [w*4, w*4+4).
// ---------------------------------------------------------------------------
__device__ void merge_stage(int w,
    const float* h1, const float* part,
    const float* f2b, const float* g2, const float* bt2,
    float* hout, unsigned short* hbf,
    const float* outW, const float* outb, float* out, int doFinal, int tid)
{
    int row = w * 4 + (tid >> 6);
    int lane = tid & 63;
    int d = lane * 4;

    float4 z = *(const float4*)(h1 + (size_t)row * 256 + d);
    float4 b4 = *(const float4*)(f2b + d);
    z.x += b4.x; z.y += b4.y; z.z += b4.z; z.w += b4.w;
#pragma unroll
    for (int c = 0; c < 4; ++c) {
        float4 p = *(const float4*)(part + ((size_t)c * 4096 + row) * 256 + d);
        z.x += p.x; z.y += p.y; z.z += p.z; z.w += p.w;
    }

    float s = z.x + z.y + z.z + z.w;
    float ss = z.x * z.x + z.y * z.y + z.z * z.z + z.w * z.w;
#pragma unroll
    for (int off = 1; off < 64; off <<= 1) {
        s += __shfl_xor(s, off);
        ss += __shfl_xor(ss, off);
    }
    float mean = s * (1.f / 256.f);
    float var = ss * (1.f / 256.f) - mean * mean;
    float inv = rsqrtf(var + 1e-5f);

    float4 g4 = *(const float4*)(g2 + d);
    float4 t4 = *(const float4*)(bt2 + d);
    float4 o;
    o.x = (z.x - mean) * inv * g4.x + t4.x;
    o.y = (z.y - mean) * inv * g4.y + t4.y;
    o.z = (z.z - mean) * inv * g4.z + t4.z;
    o.w = (z.w - mean) * inv * g4.w + t4.w;
    *(float4*)(hout + (size_t)row * 256 + d) = o;
    unsigned int u01 = (unsigned)f2bf(o.x) | ((unsigned)f2bf(o.y) << 16);
    unsigned int u23 = (unsigned)f2bf(o.z) | ((unsigned)f2bf(o.w) << 16);
    *(uint2*)&hbf[(size_t)row * 256 + d] = make_uint2(u01, u23);

    if (doFinal && (row == 2047 || row == 4095)) {
        float4 w4 = *(const float4*)(outW + d);
        float s2 = o.x * w4.x + o.y * w4.y + o.z * w4.z + o.w * w4.w;
#pragma unroll
        for (int off = 1; off < 64; off <<= 1) s2 += __shfl_xor(s2, off);
        if (lane == 0) out[row >> 11] = s2 * 0.5f + outb[0];
    }
}

// ---------------------------------------------------------------------------
// Cooperative megakernel: grid 256 x 256 threads (1 block/CU co-residency).
// ---------------------------------------------------------------------------
__global__ void __launch_bounds__(256) mega(MP P)
{
    __shared__ Smem S;
    cg::grid_group grid = cg::this_grid();
    int bx = blockIdx.x, tid = threadIdx.x;

    prep_stage(P, bx, 256, tid);
    __threadfence();
    grid.sync();

    for (int l = 0; l < L_; ++l) {
        const unsigned short* wq_l  = P.wq  + (size_t)l * D_ * D_;
        const unsigned short* wk_l  = P.wk  + (size_t)l * D_ * D_;
        const unsigned short* wv_l  = P.wv  + (size_t)l * D_ * D_;
        const unsigned short* wo_l  = P.wo  + (size_t)l * D_ * D_;
        const unsigned short* wf1_l = P.wf1 + (size_t)l * DFF_ * D_;
        const unsigned short* wf2_l = P.wf2 + (size_t)l * DFF_ * D_;
        float* vtail_l = P.vtail + l * B_ * 256;

        for (int w = bx; w < 768; w += 256)
            qkv_stage(S, w, P.h_bf, wq_l, wk_l, wv_l,
                      P.qb + l * D_, P.kb + l * D_, P.vb + l * D_,
                      P.q_bf, P.k_bf, P.v_bf, P.td + l * H_, vtail_l, tid);
        __threadfence();
        grid.sync();

        for (int p = bx; p < 512; p += 256)
            attn_stage(S, p, P.q_bf, P.k_bf, P.v_bf, vtail_l, P.ctx_bf,
                       P.scale + l, P.td + l * H_, tid);
        __threadfence();
        grid.sync();

        for (int w = bx; w < 512; w += 256)
            oproj_stage(S, w, P.ctx_bf, wo_l, P.ob + l * D_, P.h,
                        P.ln1g + l * D_, P.ln1b + l * D_, P.h1, P.h1_bf, tid);
        __threadfence();
        grid.sync();

        for (int w = bx; w < 512; w += 256)
            ffn_stage(S, w, P.h1_bf, wf1_l, P.f1b + l * DFF_, wf2_l, P.part, tid);
        __threadfence();
        grid.sync();

        for (int w = bx; w < 1024; w += 256)
            merge_stage(w, P.h1, P.part, P.f2b + l * D_,
                        P.ln2g + l * D_, P.ln2b + l * D_,
                        P.h, P.h_bf, P.outW, P.outb, P.out,
                        (l == L_ - 1) ? 1 : 0, tid);
        __threadfence();
        grid.sync();
    }
}

// ---------------------------------------------------------------------------
// Fallback wrappers (regular launches, round-11-equivalent schedule).
// ---------------------------------------------------------------------------
__global__ __launch_bounds__(256) void prep_wrap(MP P) {
    prep_stage(P, blockIdx.x, gridDim.x, threadIdx.x);
}
__global__ __launch_bounds__(256) void qkv_wrap(MP P, int l) {
    __shared__ Smem S;
    qkv_stage(S, blockIdx.x, P.h_bf,
              P.wq + (size_t)l * D_ * D_, P.wk + (size_t)l * D_ * D_,
              P.wv + (size_t)l * D_ * D_,
              P.qb + l * D_, P.kb + l * D_, P.vb + l * D_,
              P.q_bf, P.k_bf, P.v_bf, P.td + l * H_,
              P.vtail + l * B_ * 256, threadIdx.x);
}
__global__ __launch_bounds__(256) void attn_wrap(MP P, int l) {
    __shared__ Smem S;
    attn_stage(S, blockIdx.x, P.q_bf, P.k_bf, P.v_bf,
               P.vtail + l * B_ * 256, P.ctx_bf,
               P.scale + l, P.td + l * H_, threadIdx.x);
}
__global__ __launch_bounds__(256) void oproj_wrap(MP P, int l) {
    __shared__ Smem S;
    oproj_stage(S, blockIdx.x, P.ctx_bf, P.wo + (size_t)l * D_ * D_,
                P.ob + l * D_, P.h, P.ln1g + l * D_, P.ln1b + l * D_,
                P.h1, P.h1_bf, threadIdx.x);
}
__global__ __launch_bounds__(256) void ffn_wrap(MP P, int l) {
    __shared__ Smem S;
    ffn_stage(S, blockIdx.x, P.h1_bf, P.wf1 + (size_t)l * DFF_ * D_,
              P.f1b + l * DFF_, P.wf2 + (size_t)l * DFF_ * D_,
              P.part, threadIdx.x);
}
__global__ __launch_bounds__(256) void merge_wrap(MP P, int l) {
    merge_stage(blockIdx.x, P.h1, P.part, P.f2b + l * D_,
                P.ln2g + l * D_, P.ln2b + l * D_,
                P.h, P.h_bf, P.outW, P.outb, P.out,
                (l == L_ - 1) ? 1 : 0, threadIdx.x);
}

// ---------------------------------------------------------------------------
extern "C" void kernel_launch(void* const* d_in, const int* in_sizes, int n_in,
                              void* d_out, int out_size, void* d_ws, size_t ws_size,
                              hipStream_t stream)
{
    (void)in_sizes; (void)n_in; (void)out_size; (void)ws_size;

    float* ws = (float*)d_ws;
    const size_t MT = (size_t)B_ * SEQ_ * D_;      // 1,048,576

    MP P;
    P.x      = (const float*)d_in[0];
    P.conv_w = (const float*)d_in[1];
    P.conv_b = (const float*)d_in[2];
    P.bn_g   = (const float*)d_in[3];
    P.bn_b   = (const float*)d_in[4];
    P.pe     = (const float*)d_in[5];
    P.qW     = (const float*)d_in[6];
    P.qb     = (const float*)d_in[7];
    P.kW     = (const float*)d_in[8];
    P.kb     = (const float*)d_in[9];
    P.vW     = (const float*)d_in[10];
    P.vb     = (const float*)d_in[11];
    P.oW     = (const float*)d_in[12];
    P.ob     = (const float*)d_in[13];
    P.scale  = (const float*)d_in[14];
    P.td     = (const float*)d_in[15];
    P.ln1g   = (const float*)d_in[16];
    P.ln1b   = (const float*)d_in[17];
    P.f1W    = (const float*)d_in[18];
    P.f1b    = (const float*)d_in[19];
    P.f2W    = (const float*)d_in[20];
    P.f2b    = (const float*)d_in[21];
    P.ln2g   = (const float*)d_in[22];
    P.ln2b   = (const float*)d_in[23];
    P.outW   = (const float*)d_in[24];
    P.outb   = (const float*)d_in[25];
    P.out    = (float*)d_out;

    P.h     = ws;                                  // MT fp32
    P.h1    = ws + MT;                             // MT fp32
    P.part  = ws + 2 * MT;                         // 4*MT fp32
    P.vtail = ws + 6 * MT;                         // L*B*256 fp32
    unsigned short* bfb = (unsigned short*)(ws + 6 * MT + 1024);
    P.h_bf   = bfb;
    P.ctx_bf = bfb + MT;
    P.q_bf   = bfb + 2 * MT;
    P.k_bf   = bfb + 3 * MT;
    P.v_bf   = bfb + 4 * MT;
    P.h1_bf  = bfb + 5 * MT;
    P.wq  = bfb + 6 * MT;
    P.wk  = P.wq + MT / 8;
    P.wv  = P.wk + MT / 8;
    P.wo  = P.wv + MT / 8;
    P.wf1 = P.wo + MT / 8;
    P.wf2 = P.wf1 + MT / 2;

    // deterministic decision: cooperative path only if the runtime confirms
    // at least 1 co-resident block per CU (grid 256 = 1 block/CU).
    bool coop = false;
    int maxB = 0;
    if (hipOccupancyMaxActiveBlocksPerMultiprocessor(&maxB, mega, 256, 0) == hipSuccess
        && maxB >= 1) {
        void* args[] = { &P };
        coop = (hipLaunchCooperativeKernel((const void*)mega, dim3(256), dim3(256),
                                           args, 0, stream) == hipSuccess);
    }

    if (!coop) {
        prep_wrap<<<1024, 256, 0, stream>>>(P);
        for (int l = 0; l < L_; ++l) {
            qkv_wrap  <<<768, 256, 0, stream>>>(P, l);
            attn_wrap <<<512, 256, 0, stream>>>(P, l);
            oproj_wrap<<<512, 256, 0, stream>>>(P, l);
            ffn_wrap  <<<512, 256, 0, stream>>>(P, l);
            merge_wrap<<<1024, 256, 0, stream>>>(P, l);
        }
    }
}

// Round 14
// 206.315 us; speedup vs baseline: 1.4622x; 1.4622x over previous
//
#include <hip/hip_runtime.h>
#include <math.h>

#define B_    2
#define SEQ_  2048
#define D_    256
#define H_    8
#define DK_   32
#define L_    2
#define DFF_  1024

#define TD_CUT 44.0f

typedef short  bf16x8 __attribute__((ext_vector_type(8)));
typedef float  f32x4  __attribute__((ext_vector_type(4)));

__device__ __forceinline__ int compute_kcut(float tdv) {
    int kcut = SEQ_;
    if (tdv > 1e-9f) {
        float kc = TD_CUT / tdv;
        kcut = (kc >= (float)SEQ_) ? SEQ_ : ((int)kc + 1);
    }
    int kcr = (kcut + 31) & ~31;
    if (kcr > SEQ_) kcr = SEQ_;
    return kcr;
}

__device__ __forceinline__ unsigned short f2bf(float f) {
    unsigned int u = __float_as_uint(f);
    unsigned int r = u + 0x7FFFu + ((u >> 16) & 1u);   // RNE
    return (unsigned short)(r >> 16);
}
__device__ __forceinline__ float bf2f(unsigned short u) {
    return __uint_as_float(((unsigned int)u) << 16);
}

__device__ __forceinline__ void gload_lds16(const unsigned short* g, unsigned short* l) {
    __builtin_amdgcn_global_load_lds(
        (const __attribute__((address_space(1))) unsigned int*)(const unsigned int*)g,
        (__attribute__((address_space(3))) unsigned int*)(unsigned int*)l,
        16, 0, 0);
}

// ---------------------------------------------------------------------------
// Kernel 1: prep = weight cvt (blocks 0..767) + conv/pe (rest) + vtail zero.
// ---------------------------------------------------------------------------
__global__ __launch_bounds__(256) void prep_kernel(
    const float* __restrict__ x, const float* __restrict__ w,
    const float* __restrict__ cb, const float* __restrict__ bg,
    const float* __restrict__ bb, const float* __restrict__ pe,
    float* __restrict__ h, unsigned short* __restrict__ hbf,
    const float* __restrict__ p0, const float* __restrict__ p1,
    const float* __restrict__ p2, const float* __restrict__ p3,
    const float* __restrict__ p4, const float* __restrict__ p5,
    unsigned short* __restrict__ q0, unsigned short* __restrict__ q1,
    unsigned short* __restrict__ q2, unsigned short* __restrict__ q3,
    unsigned short* __restrict__ q4, unsigned short* __restrict__ q5,
    float* __restrict__ vtail)
{
    int bid = blockIdx.x;
    if (bid < 4) vtail[bid * 256 + threadIdx.x] = 0.f;   // L*B*256 = 1024 floats
    if (bid < 768) {                              // ---- cvt path
        int t = bid * 256 + threadIdx.x;
        const float* src; unsigned short* dst; int base;
        if (t < 65536) {
            int a = t >> 14;
            src = a == 0 ? p0 : a == 1 ? p1 : a == 2 ? p2 : p3;
            dst = a == 0 ? q0 : a == 1 ? q1 : a == 2 ? q2 : q3;
            base = (t & 16383) * 8;
        } else {
            int u = t - 65536;
            int a = u >> 16;
            src = a ? p5 : p4;
            dst = a ? q5 : q4;
            base = (u & 65535) * 8;
        }
        float4 v0 = *(const float4*)(src + base);
        float4 v1 = *(const float4*)(src + base + 4);
        bf16x8 o;
        o[0] = (short)f2bf(v0.x); o[1] = (short)f2bf(v0.y);
        o[2] = (short)f2bf(v0.z); o[3] = (short)f2bf(v0.w);
        o[4] = (short)f2bf(v1.x); o[5] = (short)f2bf(v1.y);
        o[6] = (short)f2bf(v1.z); o[7] = (short)f2bf(v1.w);
        *(bf16x8*)(dst + base) = o;
        return;
    }
    // ---- conv path
    int idx = (bid - 768) * 256 + threadIdx.x;    // b*SEQ*D + s*D + d
    int d = idx & 255;
    int s = (idx >> 8) & 2047;
    int b = idx >> 19;

    const float* xp = x + b * SEQ_;
    float xm1 = (s > 0)        ? xp[s - 1] : 0.f;
    float x0  = xp[s];
    float xp1 = (s < SEQ_ - 1) ? xp[s + 1] : 0.f;

    float acc = xm1 * w[d * 3 + 0] + x0 * w[d * 3 + 1] + xp1 * w[d * 3 + 2];
    acc += cb[d];
    acc = acc * rsqrtf(1.f + 1e-5f) * bg[d] + bb[d];
    acc = fmaxf(acc, 0.f);
    float v = acc + pe[s * D_ + d];
    h[idx] = v;
    hbf[idx] = f2bf(v);
}

// ---------------------------------------------------------------------------
// Kernel 2: q/k/v GEMM (bf16 in/out); z==2 accumulates vtail[b][col] via
// device-scope atomicAdd. z==1 (K): tiles whose rows are all >= kcut of both
// covered heads produce output no kernel ever reads -> early exit.
// ---------------------------------------------------------------------------
__global__ __launch_bounds__(256) void gemm_qkv(
    const unsigned short* __restrict__ A,
    const unsigned short* __restrict__ W0, const unsigned short* __restrict__ W1,
    const unsigned short* __restrict__ W2,
    const float* __restrict__ b0, const float* __restrict__ b1,
    const float* __restrict__ b2,
    unsigned short* __restrict__ O0, unsigned short* __restrict__ O1,
    unsigned short* __restrict__ O2,
    const float* __restrict__ td_l, float* __restrict__ vtail_l,
    int M, int N, int K)
{
    int z = blockIdx.z;
    const unsigned short* W = (z == 0) ? W0 : (z == 1) ? W1 : W2;
    const float* bias = (z == 0) ? b0 : (z == 1) ? b1 : b2;
    unsigned short* C = (z == 0) ? O0 : (z == 1) ? O1 : O2;

    __shared__ unsigned short As[64 * 32];
    __shared__ unsigned short Bs[64 * 32];
    __shared__ float vsc[4][2][16];

    int tid  = threadIdx.x;
    int wave = tid >> 6, lane = tid & 63;
    int wm = (wave & 1) * 32, wn = (wave >> 1) * 32;
    int bm = blockIdx.y * 64, bn = blockIdx.x * 64;

    // K-projection dead-tile skip: attention reads K rows < kcut(head) only.
    if (z == 1) {
        int kA = compute_kcut(td_l[bn >> 5]);
        int kB = compute_kcut(td_l[(bn + 32) >> 5]);
        int kmax = kA > kB ? kA : kB;
        if ((bm & 2047) >= kmax) return;          // uniform across block
    }

    int sr  = tid >> 2;
    int scb = (tid & 3) ^ ((sr >> 1) & 3);
    const unsigned short* aG = A + (size_t)(bm + sr) * K + scb * 8;
    const unsigned short* wG = W + (size_t)(bn + sr) * K + scb * 8;
    unsigned short* aL = &As[tid * 8];
    unsigned short* bL = &Bs[tid * 8];

    int fr = lane & 15;
    int kb = lane >> 4;
    int cb = (kb ^ ((fr >> 1) & 3)) * 8;
    int oA0 = (wm + fr) * 32 + cb;
    int oA1 = (wm + 16 + fr) * 32 + cb;
    int oB0 = (wn + fr) * 32 + cb;
    int oB1 = (wn + 16 + fr) * 32 + cb;

    f32x4 acc[2][2];
#pragma unroll
    for (int i = 0; i < 2; ++i)
#pragma unroll
        for (int j = 0; j < 2; ++j) acc[i][j] = (f32x4){0.f, 0.f, 0.f, 0.f};

    for (int k0 = 0; k0 < K; k0 += 32) {
        __syncthreads();
        gload_lds16(aG + k0, aL);
        gload_lds16(wG + k0, bL);
        __syncthreads();

        bf16x8 a0f = *(const bf16x8*)&As[oA0];
        bf16x8 a1f = *(const bf16x8*)&As[oA1];
        bf16x8 b0f = *(const bf16x8*)&Bs[oB0];
        bf16x8 b1f = *(const bf16x8*)&Bs[oB1];

        acc[0][0] = __builtin_amdgcn_mfma_f32_16x16x32_bf16(a0f, b0f, acc[0][0], 0, 0, 0);
        acc[0][1] = __builtin_amdgcn_mfma_f32_16x16x32_bf16(a0f, b1f, acc[0][1], 0, 0, 0);
        acc[1][0] = __builtin_amdgcn_mfma_f32_16x16x32_bf16(a1f, b0f, acc[1][0], 0, 0, 0);
        acc[1][1] = __builtin_amdgcn_mfma_f32_16x16x32_bf16(a1f, b1f, acc[1][1], 0, 0, 0);
    }

    int crow = (lane >> 4) * 4;
    int ccol = lane & 15;
    float psum[2] = {0.f, 0.f};
    int kc2[2];
    kc2[0] = compute_kcut(td_l[(bn + wn) >> 5]);
    kc2[1] = compute_kcut(td_l[(bn + wn + 16) >> 5]);

#pragma unroll
    for (int j = 0; j < 2; ++j) {
        float bj = bias[bn + wn + j * 16 + ccol];
#pragma unroll
        for (int i = 0; i < 2; ++i) {
#pragma unroll
            for (int r = 0; r < 4; ++r) {
                float v = acc[i][j][r] + bj;
                unsigned short ubf = f2bf(v);
                C[(size_t)(bm + wm + i * 16 + crow + r) * N + bn + wn + j * 16 + ccol] = ubf;
                if (z == 2) {
                    int srow = (bm + wm + i * 16 + crow + r) & 2047;
                    if (srow >= kc2[j]) psum[j] += bf2f(ubf);
                }
            }
        }
    }

    if (z == 2) {
#pragma unroll
        for (int j = 0; j < 2; ++j) {
            psum[j] += __shfl_xor(psum[j], 16);
            psum[j] += __shfl_xor(psum[j], 32);
        }
        if (lane < 16) { vsc[wave][0][lane] = psum[0]; vsc[wave][1][lane] = psum[1]; }
        __syncthreads();
        if (tid < 64) {
            int wh = tid >> 5, jj = (tid >> 4) & 1, cc = tid & 15;
            float s = vsc[2 * wh][jj][cc] + vsc[2 * wh + 1][jj][cc];
            int b = blockIdx.y >> 5;       // 64-row blocks, 2048 rows/batch
            atomicAdd(&vtail_l[b * 256 + bn + wh * 32 + jj * 16 + cc], s);
        }
    }
}

// ---------------------------------------------------------------------------
// Kernel 3: decay-truncated flash attention, 4-way key-split + LDS merge.
// vtail[b][256] precomputed by gemm_qkv.
// ---------------------------------------------------------------------------
__global__ __launch_bounds__(128) void attn_kernel(
    const unsigned short* __restrict__ q, const unsigned short* __restrict__ k,
    const unsigned short* __restrict__ v, const float* __restrict__ vtail_l,
    unsigned short* __restrict__ ctxbf,
    const float* __restrict__ scale_p, const float* __restrict__ td_l)
{
    int b = blockIdx.z, hh = blockIdx.y;
    int tid = threadIdx.x;
    int row = tid >> 2;
    int sp  = tid & 3;
    int qrow = blockIdx.x * 32 + row;

    float sc  = 0.17677669529663687f * scale_p[0];
    float tdv = td_l[hh];
    int kcr = compute_kcut(tdv);
    int ntiles = kcr >> 5;

    __shared__ float kt[32][36];
    __shared__ float vt[32][36];
    __shared__ float Os[4][32][36];
    __shared__ float ms[4][32], ls[4][32];
    __shared__ float vts[32];

    if (tid < 32) vts[tid] = vtail_l[b * 256 + hh * 32 + tid];

    const unsigned short* qptr = q + ((size_t)(b * SEQ_ + qrow)) * D_ + hh * DK_;
    float qreg[32];
#pragma unroll
    for (int j = 0; j < 4; ++j) {
        uint4 u = ((const uint4*)qptr)[j];
        qreg[j*8+0] = __uint_as_float(u.x << 16); qreg[j*8+1] = __uint_as_float(u.x & 0xFFFF0000u);
        qreg[j*8+2] = __uint_as_float(u.y << 16); qreg[j*8+3] = __uint_as_float(u.y & 0xFFFF0000u);
        qreg[j*8+4] = __uint_as_float(u.z << 16); qreg[j*8+5] = __uint_as_float(u.z & 0xFFFF0000u);
        qreg[j*8+6] = __uint_as_float(u.w << 16); qreg[j*8+7] = __uint_as_float(u.w & 0xFFFF0000u);
    }
    float O[32];
#pragma unroll
    for (int d = 0; d < 32; ++d) O[d] = 0.f;
    float mrun = -1e30f, lrun = 0.f;

    for (int t = 0; t < ntiles; ++t) {
        int k0 = t * 32;
        __syncthreads();
        {
            int r = tid >> 2, c8 = (tid & 3) * 8;
            size_t goff = ((size_t)(b * SEQ_ + k0 + r)) * D_ + hh * DK_ + c8;
            uint4 uk = *(const uint4*)(k + goff);
            uint4 uv = *(const uint4*)(v + goff);
            *(float4*)&kt[r][c8]     = make_float4(__uint_as_float(uk.x << 16), __uint_as_float(uk.x & 0xFFFF0000u),
                                                   __uint_as_float(uk.y << 16), __uint_as_float(uk.y & 0xFFFF0000u));
            *(float4*)&kt[r][c8 + 4] = make_float4(__uint_as_float(uk.z << 16), __uint_as_float(uk.z & 0xFFFF0000u),
                                                   __uint_as_float(uk.w << 16), __uint_as_float(uk.w & 0xFFFF0000u));
            *(float4*)&vt[r][c8]     = make_float4(__uint_as_float(uv.x << 16), __uint_as_float(uv.x & 0xFFFF0000u),
                                                   __uint_as_float(uv.y << 16), __uint_as_float(uv.y & 0xFFFF0000u));
            *(float4*)&vt[r][c8 + 4] = make_float4(__uint_as_float(uv.z << 16), __uint_as_float(uv.z & 0xFFFF0000u),
                                                   __uint_as_float(uv.w << 16), __uint_as_float(uv.w & 0xFFFF0000u));
        }
        __syncthreads();

        float sb[8];
        float tmax = -1e30f;
#pragma unroll
        for (int kk = 0; kk < 8; ++kk) {
            int kl = sp * 8 + kk;
            float acc = 0.f;
#pragma unroll
            for (int d4 = 0; d4 < 8; ++d4) {
                float4 kv = *(const float4*)&kt[kl][d4 * 4];
                acc += qreg[d4 * 4 + 0] * kv.x + qreg[d4 * 4 + 1] * kv.y
                     + qreg[d4 * 4 + 2] * kv.z + qreg[d4 * 4 + 3] * kv.w;
            }
            float dec = __expf(-tdv * (float)(k0 + kl));
            float sv = acc * sc * dec;
            sb[kk] = sv;
            tmax = fmaxf(tmax, sv);
        }
        float mnew = fmaxf(mrun, tmax);
        float alpha = __expf(mrun - mnew);
        lrun *= alpha;
#pragma unroll
        for (int d = 0; d < 32; ++d) O[d] *= alpha;
#pragma unroll
        for (int kk = 0; kk < 8; ++kk) {
            int kl = sp * 8 + kk;
            float sv = sb[kk];
            float e = __expf(sv - mnew);
            float sg = 1.f / (1.f + __expf(-sv));
            float p = e * sg;
            lrun += e;
#pragma unroll
            for (int d4 = 0; d4 < 8; ++d4) {
                float4 vv = *(const float4*)&vt[kl][d4 * 4];
                O[d4 * 4 + 0] += p * vv.x; O[d4 * 4 + 1] += p * vv.y;
                O[d4 * 4 + 2] += p * vv.z; O[d4 * 4 + 3] += p * vv.w;
            }
        }
        mrun = mnew;
    }

#pragma unroll
    for (int d4 = 0; d4 < 8; ++d4)
        *(float4*)&Os[sp][row][d4 * 4] =
            make_float4(O[d4*4+0], O[d4*4+1], O[d4*4+2], O[d4*4+3]);
    ms[sp][row] = mrun;
    ls[sp][row] = lrun;
    __syncthreads();

    {
        int g = sp;
        float m0 = fmaxf(fmaxf(ms[0][row], ms[1][row]), fmaxf(ms[2][row], ms[3][row]));
        float mt = (kcr < SEQ_) ? fmaxf(m0, 0.f) : m0;
        float w0 = __expf(ms[0][row] - mt), w1 = __expf(ms[1][row] - mt);
        float w2 = __expf(ms[2][row] - mt), w3 = __expf(ms[3][row] - mt);
        float Lt = ls[0][row]*w0 + ls[1][row]*w1 + ls[2][row]*w2 + ls[3][row]*w3;
        float ew = 0.f;
        if (kcr < SEQ_) {
            ew = __expf(-mt);
            Lt += (float)(SEQ_ - kcr) * ew;
        }
        float invL = 1.f / Lt;
        unsigned int packed[4];
#pragma unroll
        for (int dd = 0; dd < 8; dd += 2) {
            int d0 = g * 8 + dd, d1 = d0 + 1;
            float n0 = Os[0][row][d0]*w0 + Os[1][row][d0]*w1 + Os[2][row][d0]*w2 + Os[3][row][d0]*w3;
            float n1 = Os[0][row][d1]*w0 + Os[1][row][d1]*w1 + Os[2][row][d1]*w2 + Os[3][row][d1]*w3;
            if (kcr < SEQ_) {
                n0 += 0.5f * ew * vts[d0];
                n1 += 0.5f * ew * vts[d1];
            }
            packed[dd >> 1] = (unsigned)f2bf(n0 * invL) | ((unsigned)f2bf(n1 * invL) << 16);
        }
        unsigned short* obf = ctxbf + ((size_t)(b * SEQ_ + qrow)) * D_ + hh * DK_ + g * 8;
        *(uint4*)obf = make_uint4(packed[0], packed[1], packed[2], packed[3]);
    }
}

// ---------------------------------------------------------------------------
// Kernel 4: o-proj + residual + LN1. Block = 16 rows x 256 cols, grid M/16.
// ---------------------------------------------------------------------------
__global__ __launch_bounds__(256) void oproj_ln1(
    const unsigned short* __restrict__ ctx, const unsigned short* __restrict__ wo,
    const float* __restrict__ ob, const float* __restrict__ resid,
    const float* __restrict__ g1, const float* __restrict__ bt1,
    float* __restrict__ h1out, unsigned short* __restrict__ h1bf)
{
    __shared__ unsigned short As[16 * 32];      // 64 slots
    __shared__ unsigned short Bs[256 * 32];     // 1024 slots
    __shared__ float lsum[4][16], lsq[4][16], mean_s[16], inv_s[16];

    int tid = threadIdx.x;
    int wave = tid >> 6, lane = tid & 63;
    int bm = blockIdx.x * 16;
    int fr = lane & 15, kb = lane >> 4;
    int q = kb, cl = fr;
    int swz = (fr >> 1) & 3;

    const unsigned short* gpB[4];
    unsigned short* lpB[4];
#pragma unroll
    for (int i = 0; i < 4; ++i) {
        int sB = i * 256 + tid;
        int r = sB >> 2, ck = (sB & 3) ^ ((r >> 1) & 3);
        gpB[i] = wo + (size_t)r * 256 + ck * 8;
        lpB[i] = &Bs[sB * 8];
    }
    const unsigned short* gpA = nullptr;
    unsigned short* lpA = nullptr;
    if (tid < 64) {
        int r = tid >> 2, ck = (tid & 3) ^ ((r >> 1) & 3);
        gpA = ctx + (size_t)(bm + r) * 256 + ck * 8;
        lpA = &As[tid * 8];
    }

    int oA = fr * 32 + ((kb ^ swz) * 8);
    int oB[4];
#pragma unroll
    for (int t = 0; t < 4; ++t) {
        int n = wave * 64 + t * 16 + fr;
        oB[t] = n * 32 + ((kb ^ swz) * 8);
    }

    f32x4 acc[4];
#pragma unroll
    for (int j = 0; j < 4; ++j) acc[j] = (f32x4){0.f, 0.f, 0.f, 0.f};

    for (int k0 = 0; k0 < 256; k0 += 32) {
        __syncthreads();
#pragma unroll
        for (int i = 0; i < 4; ++i) gload_lds16(gpB[i] + k0, lpB[i]);
        if (tid < 64) gload_lds16(gpA + k0, lpA);
        __syncthreads();

        bf16x8 af = *(const bf16x8*)&As[oA];
#pragma unroll
        for (int j = 0; j < 4; ++j)
            acc[j] = __builtin_amdgcn_mfma_f32_16x16x32_bf16(
                af, *(const bf16x8*)&Bs[oB[j]], acc[j], 0, 0, 0);
    }

    float zsum[4] = {0.f, 0.f, 0.f, 0.f}, zsq[4] = {0.f, 0.f, 0.f, 0.f};
    float zv[4][4];
#pragma unroll
    for (int ct = 0; ct < 4; ++ct) {
        int col = wave * 64 + ct * 16 + cl;
        float bj = ob[col];
#pragma unroll
        for (int r = 0; r < 4; ++r) {
            int row = bm + q * 4 + r;
            float z = acc[ct][r] + bj + resid[(size_t)row * 256 + col];
            zv[ct][r] = z;
            zsum[r] += z;
            zsq[r]  += z * z;
        }
    }
#pragma unroll
    for (int r = 0; r < 4; ++r) {
#pragma unroll
        for (int off = 1; off < 16; off <<= 1) {
            zsum[r] += __shfl_xor(zsum[r], off);
            zsq[r]  += __shfl_xor(zsq[r], off);
        }
    }
    if (cl == 0) {
#pragma unroll
        for (int r = 0; r < 4; ++r) {
            lsum[wave][q * 4 + r] = zsum[r];
            lsq[wave][q * 4 + r]  = zsq[r];
        }
    }
    __syncthreads();
    if (tid < 16) {
        float s  = lsum[0][tid] + lsum[1][tid] + lsum[2][tid] + lsum[3][tid];
        float sq = lsq[0][tid] + lsq[1][tid] + lsq[2][tid] + lsq[3][tid];
        float mean = s * (1.f / 256.f);
        float var  = sq * (1.f / 256.f) - mean * mean;
        mean_s[tid] = mean;
        inv_s[tid]  = rsqrtf(var + 1e-5f);
    }
    __syncthreads();

#pragma unroll
    for (int ct = 0; ct < 4; ++ct) {
        int col = wave * 64 + ct * 16 + cl;
        float gc = g1[col], bc = bt1[col];
#pragma unroll
        for (int r = 0; r < 4; ++r) {
            int lr = q * 4 + r;
            float o = (zv[ct][r] - mean_s[lr]) * inv_s[lr] * gc + bc;
            size_t off = (size_t)(bm + lr) * 256 + col;
            h1out[off] = o;
            h1bf[off]  = f2bf(o);
        }
    }
}

// ---------------------------------------------------------------------------
// Kernel 5: fused FFN chunk. Block = 32 rows x 256-of-1024 ff-cols.
// grid (4, M/32) = 512 blocks.
// ---------------------------------------------------------------------------
__global__ __launch_bounds__(256) void ffn_fused(
    const unsigned short* __restrict__ h1bf, const unsigned short* __restrict__ w1,
    const float* __restrict__ f1b, const unsigned short* __restrict__ w2,
    float* __restrict__ part)
{
    __shared__ unsigned short As[32 * 32];      // 128 slots (h1 K-slab)
    __shared__ unsigned short Bs[256 * 32];     // 1024 slots (weight K-slab)
    __shared__ unsigned short ffs[32 * 264];    // relu chunk, bf16 (16.5 KB)

    int tid = threadIdx.x;
    int wave = tid >> 6, lane = tid & 63;
    int c = blockIdx.x;           // ff-chunk 0..3
    int bm = blockIdx.y * 32;
    int fr = lane & 15, kb = lane >> 4;
    int q = kb, cl = fr;
    int swz = (fr >> 1) & 3;

    const unsigned short* gA = nullptr;
    unsigned short* lA = nullptr;
    if (tid < 128) {
        int ar = tid >> 2, ack = (tid & 3) ^ ((ar >> 1) & 3);
        gA = h1bf + (size_t)(bm + ar) * 256 + ack * 8;
        lA = &As[tid * 8];
    }

    int oA1[2], oB[4];
#pragma unroll
    for (int t = 0; t < 2; ++t) {
        int m = t * 16 + fr;
        oA1[t] = m * 32 + ((kb ^ ((m >> 1) & 3)) * 8);
    }
#pragma unroll
    for (int t = 0; t < 4; ++t) {
        int n = wave * 64 + t * 16 + fr;
        oB[t] = n * 32 + ((kb ^ ((n >> 1) & 3)) * 8);
    }

    f32x4 a1[2][4];
#pragma unroll
    for (int i = 0; i < 2; ++i)
#pragma unroll
        for (int j = 0; j < 4; ++j) a1[i][j] = (f32x4){0.f, 0.f, 0.f, 0.f};

    for (int ks = 0; ks < 8; ++ks) {
        __syncthreads();
        if (tid < 128) gload_lds16(gA + ks * 32, lA);
#pragma unroll
        for (int i = 0; i < 4; ++i) {
            int sB = i * 256 + tid;
            int r = sB >> 2, ck = (sB & 3) ^ ((r >> 1) & 3);
            gload_lds16(w1 + (size_t)(c * 256 + r) * 256 + ks * 32 + ck * 8, &Bs[sB * 8]);
        }
        __syncthreads();

        bf16x8 af[2], bfv[4];
#pragma unroll
        for (int t = 0; t < 2; ++t) af[t] = *(const bf16x8*)&As[oA1[t]];
#pragma unroll
        for (int t = 0; t < 4; ++t) bfv[t] = *(const bf16x8*)&Bs[oB[t]];
#pragma unroll
        for (int i = 0; i < 2; ++i)
#pragma unroll
            for (int j = 0; j < 4; ++j)
                a1[i][j] = __builtin_amdgcn_mfma_f32_16x16x32_bf16(af[i], bfv[j], a1[i][j], 0, 0, 0);
    }

#pragma unroll
    for (int ct = 0; ct < 4; ++ct) {
        int col = wave * 64 + ct * 16 + cl;
        float bj = f1b[c * 256 + col];
#pragma unroll
        for (int rt = 0; rt < 2; ++rt)
#pragma unroll
            for (int r = 0; r < 4; ++r) {
                float v = fmaxf(a1[rt][ct][r] + bj, 0.f);
                ffs[(rt * 16 + q * 4 + r) * 264 + col] = f2bf(v);
            }
    }

    f32x4 a2[2][4];
#pragma unroll
    for (int i = 0; i < 2; ++i)
#pragma unroll
        for (int j = 0; j < 4; ++j) a2[i][j] = (f32x4){0.f, 0.f, 0.f, 0.f};

    for (int ks = 0; ks < 8; ++ks) {
        __syncthreads();     // first iter: also publishes ffs, drains Bs reads
#pragma unroll
        for (int i = 0; i < 4; ++i) {
            int sB = i * 256 + tid;
            int r = sB >> 2, ck = (sB & 3) ^ ((r >> 1) & 3);
            gload_lds16(w2 + (size_t)r * 1024 + c * 256 + ks * 32 + ck * 8, &Bs[sB * 8]);
        }
        __syncthreads();

        bf16x8 af[2], bfv[4];
#pragma unroll
        for (int t = 0; t < 2; ++t)
            af[t] = *(const bf16x8*)&ffs[(t * 16 + fr) * 264 + ks * 32 + kb * 8];
#pragma unroll
        for (int t = 0; t < 4; ++t) bfv[t] = *(const bf16x8*)&Bs[oB[t]];
#pragma unroll
        for (int i = 0; i < 2; ++i)
#pragma unroll
            for (int j = 0; j < 4; ++j)
                a2[i][j] = __builtin_amdgcn_mfma_f32_16x16x32_bf16(af[i], bfv[j], a2[i][j], 0, 0, 0);
    }

#pragma unroll
    for (int ct = 0; ct < 4; ++ct) {
        int col = wave * 64 + ct * 16 + cl;
#pragma unroll
        for (int rt = 0; rt < 2; ++rt)
#pragma unroll
            for (int r = 0; r < 4; ++r)
                part[((size_t)c * 4096 + bm + rt * 16 + q * 4 + r) * 256 + col] = a2[rt][ct][r];
    }
}

// ---------------------------------------------------------------------------
// Kernel 6: merge FFN2 partials + bias + h1 residual + LN2 (+final fold).
// ---------------------------------------------------------------------------
__global__ __launch_bounds__(256) void merge_ln2(
    const float* __restrict__ h1, const float* __restrict__ part,
    const float* __restrict__ f2b, const float* __restrict__ g2,
    const float* __restrict__ bt2,
    float* __restrict__ hout, unsigned short* __restrict__ hbf,
    const float* __restrict__ outW, const float* __restrict__ outb,
    float* __restrict__ out, int doFinal)
{
    int row = blockIdx.x * 4 + (threadIdx.x >> 6);
    int lane = threadIdx.x & 63;
    int d = lane * 4;

    float4 z = *(const float4*)(h1 + (size_t)row * 256 + d);
    float4 b4 = *(const float4*)(f2b + d);
    z.x += b4.x; z.y += b4.y; z.z += b4.z; z.w += b4.w;
#pragma unroll
    for (int c = 0; c < 4; ++c) {
        float4 p = *(const float4*)(part + ((size_t)c * 4096 + row) * 256 + d);
        z.x += p.x; z.y += p.y; z.z += p.z; z.w += p.w;
    }

    float s = z.x + z.y + z.z + z.w;
    float ss = z.x * z.x + z.y * z.y + z.z * z.z + z.w * z.w;
#pragma unroll
    for (int off = 1; off < 64; off <<= 1) {
        s += __shfl_xor(s, off);
        ss += __shfl_xor(ss, off);
    }
    float mean = s * (1.f / 256.f);
    float var = ss * (1.f / 256.f) - mean * mean;
    float inv = rsqrtf(var + 1e-5f);

    float4 g4 = *(const float4*)(g2 + d);
    float4 t4 = *(const float4*)(bt2 + d);
    float4 o;
    o.x = (z.x - mean) * inv * g4.x + t4.x;
    o.y = (z.y - mean) * inv * g4.y + t4.y;
    o.z = (z.z - mean) * inv * g4.z + t4.z;
    o.w = (z.w - mean) * inv * g4.w + t4.w;
    *(float4*)(hout + (size_t)row * 256 + d) = o;
    unsigned int u01 = (unsigned)f2bf(o.x) | ((unsigned)f2bf(o.y) << 16);
    unsigned int u23 = (unsigned)f2bf(o.z) | ((unsigned)f2bf(o.w) << 16);
    *(uint2*)&hbf[(size_t)row * 256 + d] = make_uint2(u01, u23);

    if (doFinal && (row == 2047 || row == 4095)) {
        float4 w4 = *(const float4*)(outW + d);
        float s2 = o.x * w4.x + o.y * w4.y + o.z * w4.z + o.w * w4.w;
#pragma unroll
        for (int off = 1; off < 64; off <<= 1) s2 += __shfl_xor(s2, off);
        if (lane == 0) out[row >> 11] = s2 * 0.5f + outb[0];
    }
}

// ---------------------------------------------------------------------------
extern "C" void kernel_launch(void* const* d_in, const int* in_sizes, int n_in,
                              void* d_out, int out_size, void* d_ws, size_t ws_size,
                              hipStream_t stream)
{
    (void)in_sizes; (void)n_in; (void)out_size; (void)ws_size;
    const float* x      = (const float*)d_in[0];
    const float* conv_w = (const float*)d_in[1];
    const float* conv_b = (const float*)d_in[2];
    const float* bn_g   = (const float*)d_in[3];
    const float* bn_b   = (const float*)d_in[4];
    const float* pe     = (const float*)d_in[5];
    const float* qW     = (const float*)d_in[6];
    const float* qb     = (const float*)d_in[7];
    const float* kW     = (const float*)d_in[8];
    const float* kb     = (const float*)d_in[9];
    const float* vW     = (const float*)d_in[10];
    const float* vb     = (const float*)d_in[11];
    const float* oW     = (const float*)d_in[12];
    const float* ob     = (const float*)d_in[13];
    const float* scale  = (const float*)d_in[14];
    const float* td     = (const float*)d_in[15];
    const float* ln1g   = (const float*)d_in[16];
    const float* ln1b   = (const float*)d_in[17];
    const float* f1W    = (const float*)d_in[18];
    const float* f1b    = (const float*)d_in[19];
    const float* f2W    = (const float*)d_in[20];
    const float* f2b    = (const float*)d_in[21];
    const float* ln2g   = (const float*)d_in[22];
    const float* ln2b   = (const float*)d_in[23];
    const float* outW   = (const float*)d_in[24];
    const float* outb   = (const float*)d_in[25];
    float* out = (float*)d_out;

    float* ws = (float*)d_ws;
    const size_t MT = (size_t)B_ * SEQ_ * D_;      // 1,048,576
    float* h     = ws;                             // MT fp32
    float* h1    = ws + MT;                        // MT fp32
    float* part  = ws + 2 * MT;                    // 4*MT fp32
    float* vtail = ws + 6 * MT;                    // 1024 fp32 (L*B*256)
    unsigned short* bfb = (unsigned short*)(ws + 6 * MT + 1024);
    unsigned short* h_bf   = bfb;
    unsigned short* ctx_bf = bfb + MT;
    unsigned short* q_bf   = bfb + 2 * MT;
    unsigned short* k_bf   = bfb + 3 * MT;
    unsigned short* v_bf   = bfb + 4 * MT;
    unsigned short* h1_bf  = bfb + 5 * MT;
    unsigned short* wq_bf  = bfb + 6 * MT;
    unsigned short* wk_bf  = wq_bf + MT / 8;
    unsigned short* wv_bf  = wk_bf + MT / 8;
    unsigned short* wo_bf  = wv_bf + MT / 8;
    unsigned short* wf1_bf = wo_bf + MT / 8;
    unsigned short* wf2_bf = wf1_bf + MT / 2;

    const int Mrows = B_ * SEQ_;                   // 4096

    prep_kernel<<<768 + (B_ * SEQ_ * D_) / 256, 256, 0, stream>>>(
        x, conv_w, conv_b, bn_g, bn_b, pe, h, h_bf,
        qW, kW, vW, oW, f1W, f2W,
        wq_bf, wk_bf, wv_bf, wo_bf, wf1_bf, wf2_bf, vtail);

    for (int l = 0; l < L_; ++l) {
        const unsigned short* wq_l  = wq_bf  + (size_t)l * D_ * D_;
        const unsigned short* wk_l  = wk_bf  + (size_t)l * D_ * D_;
        const unsigned short* wv_l  = wv_bf  + (size_t)l * D_ * D_;
        const unsigned short* wo_l  = wo_bf  + (size_t)l * D_ * D_;
        const unsigned short* wf1_l = wf1_bf + (size_t)l * DFF_ * D_;
        const unsigned short* wf2_l = wf2_bf + (size_t)l * DFF_ * D_;
        float* vtail_l = vtail + l * B_ * 256;

        gemm_qkv<<<dim3(D_ / 64, Mrows / 64, 3), 256, 0, stream>>>(
            h_bf, wq_l, wk_l, wv_l, qb + l * D_, kb + l * D_, vb + l * D_,
            q_bf, k_bf, v_bf, td + l * H_, vtail_l, Mrows, D_, D_);

        attn_kernel<<<dim3(SEQ_ / 32, H_, B_), 128, 0, stream>>>(
            q_bf, k_bf, v_bf, vtail_l, ctx_bf, scale + l, td + l * H_);

        oproj_ln1<<<Mrows / 16, 256, 0, stream>>>(
            ctx_bf, wo_l, ob + l * D_, h,
            ln1g + l * D_, ln1b + l * D_, h1, h1_bf);

        ffn_fused<<<dim3(4, Mrows / 32), 256, 0, stream>>>(
            h1_bf, wf1_l, f1b + l * DFF_, wf2_l, part);

        merge_ln2<<<Mrows / 4, 256, 0, stream>>>(
            h1, part, f2b + l * D_, ln2g + l * D_, ln2b + l * D_,
            h, h_bf, outW, outb, out, (l == L_ - 1) ? 1 : 0);
    }
}